// Round 1
// baseline (19996.431 us; speedup 1.0000x reference)
//
#include <hip/hip_runtime.h>
#include <math.h>

// ---------------------------------------------------------------------------
// Faster R-CNN forward on MI355X — round 1:
//  * split-K fp32 GEMM for fc6/fc7 (occupancy fix: 304 -> 640 blocks, 8x8 tile)
//  * conv3x3 stages 4 channels per barrier (4x fewer __syncthreads per FMA)
//  * bitonic sort fused into LDS-local phases (120 -> 14 launches)
//  * NMS sequential scan as a single wave64 with register keep-mask + prefetch
//  * select_rois parallel rank-scatter (was single-thread 12000-read loop)
// ---------------------------------------------------------------------------

#define NPOS 2294      // 37*62 RPN positions
#define FH 37
#define FW 62
#define NANCH 20646    // NPOS*9
#define NSORT 32768
#define PRE_NMS 6000
#define POST_NMS 300
#define NWORD 94       // ceil(6000/64)
#define GS 8           // GEMM split-K factor

__device__ const float ANCHORS[9][4] = {
    {-84.f,  -40.f,   99.f,  55.f},
    {-176.f, -88.f,  191.f, 103.f},
    {-360.f, -184.f, 375.f, 199.f},
    {-56.f,  -56.f,   71.f,  71.f},
    {-120.f, -120.f, 135.f, 135.f},
    {-248.f, -248.f, 263.f, 263.f},
    {-36.f,  -80.f,   51.f,  95.f},
    {-80.f,  -168.f,  95.f, 183.f},
    {-168.f, -344.f, 183.f, 359.f},
};

// ---------------- conv 3x3 SAME, optional ReLU, 8 out-ch/block --------------
// Stages 4 input channels per barrier round (sync amortization).
__global__ __launch_bounds__(256) void conv3x3(
    const float* __restrict__ in, const float* __restrict__ w,
    const float* __restrict__ bias, float* __restrict__ out,
    int C, int H, int W, int relu, int nhwc)
{
    __shared__ float patch[4][10][34];
    const int tx = threadIdx.x, ty = threadIdx.y;
    const int tid = ty * 32 + tx;
    const int x0 = blockIdx.x * 32, y0 = blockIdx.y * 8;
    const int k0 = blockIdx.z * 8;
    const size_t HW = (size_t)H * W;

    float acc[8];
#pragma unroll
    for (int i = 0; i < 8; ++i) acc[i] = 0.f;

    for (int c0 = 0; c0 < C; c0 += 4) {
        const int nc = (C - c0 >= 4) ? 4 : (C - c0);
        __syncthreads();
        for (int idx = tid; idx < nc * 340; idx += 256) {
            int cc = idx / 340, rr = idx - cc * 340;
            int py = rr / 34, px = rr - py * 34;
            int gy = y0 + py - 1, gx = x0 + px - 1;
            float v = 0.f;
            if (gy >= 0 && gy < H && gx >= 0 && gx < W)
                v = nhwc ? in[((size_t)gy * W + gx) * C + (c0 + cc)]
                         : in[(size_t)(c0 + cc) * HW + (size_t)gy * W + gx];
            patch[cc][py][px] = v;
        }
        __syncthreads();
        if (nc == 4) {
#pragma unroll
            for (int cc = 0; cc < 4; ++cc) {
                float r0 = patch[cc][ty][tx],     r1 = patch[cc][ty][tx + 1],     r2 = patch[cc][ty][tx + 2];
                float r3 = patch[cc][ty + 1][tx], r4 = patch[cc][ty + 1][tx + 1], r5 = patch[cc][ty + 1][tx + 2];
                float r6 = patch[cc][ty + 2][tx], r7 = patch[cc][ty + 2][tx + 1], r8 = patch[cc][ty + 2][tx + 2];
                const float* wp = w + ((size_t)k0 * C + (c0 + cc)) * 9;
#pragma unroll
                for (int ko = 0; ko < 8; ++ko) {
                    const float* wk = wp + (size_t)ko * C * 9;
                    acc[ko] += wk[0] * r0 + wk[1] * r1 + wk[2] * r2
                             + wk[3] * r3 + wk[4] * r4 + wk[5] * r5
                             + wk[6] * r6 + wk[7] * r7 + wk[8] * r8;
                }
            }
        } else {
            for (int cc = 0; cc < nc; ++cc) {
                float r0 = patch[cc][ty][tx],     r1 = patch[cc][ty][tx + 1],     r2 = patch[cc][ty][tx + 2];
                float r3 = patch[cc][ty + 1][tx], r4 = patch[cc][ty + 1][tx + 1], r5 = patch[cc][ty + 1][tx + 2];
                float r6 = patch[cc][ty + 2][tx], r7 = patch[cc][ty + 2][tx + 1], r8 = patch[cc][ty + 2][tx + 2];
                const float* wp = w + ((size_t)k0 * C + (c0 + cc)) * 9;
#pragma unroll
                for (int ko = 0; ko < 8; ++ko) {
                    const float* wk = wp + (size_t)ko * C * 9;
                    acc[ko] += wk[0] * r0 + wk[1] * r1 + wk[2] * r2
                             + wk[3] * r3 + wk[4] * r4 + wk[5] * r5
                             + wk[6] * r6 + wk[7] * r7 + wk[8] * r8;
                }
            }
        }
    }

    int gx = x0 + tx, gy = y0 + ty;
    if (gx < W && gy < H) {
#pragma unroll
        for (int ko = 0; ko < 8; ++ko) {
            float v = acc[ko] + bias[k0 + ko];
            if (relu) v = fmaxf(v, 0.f);
            out[(size_t)(k0 + ko) * HW + (size_t)gy * W + gx] = v;
        }
    }
}

// ---------------- 2x2 stride-2 VALID maxpool --------------------------------
__global__ void maxpool2(const float* __restrict__ in, float* __restrict__ out,
                         int C, int H, int W)
{
    int Ho = H >> 1, Wo = W >> 1;
    int total = C * Ho * Wo;
    int idx = blockIdx.x * blockDim.x + threadIdx.x;
    if (idx >= total) return;
    int c = idx / (Ho * Wo);
    int r = idx - c * (Ho * Wo);
    int y = r / Wo, x = r - y * Wo;
    const float* p = in + (size_t)c * H * W + (size_t)(2 * y) * W + 2 * x;
    out[idx] = fmaxf(fmaxf(p[0], p[1]), fmaxf(p[W], p[W + 1]));
}

// ---------------- 1x1 conv (score / bbox heads) -----------------------------
__global__ void conv1x1(const float* __restrict__ in, const float* __restrict__ w,
                        const float* __restrict__ b, float* __restrict__ out,
                        int C, int P, int K)
{
    int p = blockIdx.x * blockDim.x + threadIdx.x;
    int k = blockIdx.y;
    if (p >= P || k >= K) return;
    const float* wr = w + (size_t)k * C;
    float acc = b[k];
    for (int c = 0; c < C; ++c) acc += wr[c] * in[(size_t)c * P + p];
    out[(size_t)k * P + p] = acc;
}

// ---------------- decode anchors + softmax score + sort keys ----------------
__global__ void decode_anchors(const float* __restrict__ score,
                               const float* __restrict__ bbox,
                               const float* __restrict__ iminfo,
                               float* __restrict__ boxes,
                               unsigned long long* __restrict__ keys)
{
    int idx = blockIdx.x * blockDim.x + threadIdx.x;
    if (idx >= NSORT) return;
    if (idx >= NANCH) { keys[idx] = ~0ULL; return; }
    int p = idx / 9, a = idx - p * 9;
    int y = p / FW, x = p - y * FW;

    float s0 = score[a * NPOS + p], s1 = score[(9 + a) * NPOS + p];
    float mx = fmaxf(s0, s1);
    float e0 = expf(s0 - mx), e1 = expf(s1 - mx);
    float prob = e1 / (e0 + e1);

    float ax1 = ANCHORS[a][0] + 16.f * x;
    float ay1 = ANCHORS[a][1] + 16.f * y;
    float ax2 = ANCHORS[a][2] + 16.f * x;
    float ay2 = ANCHORS[a][3] + 16.f * y;
    float aw = ax2 - ax1 + 1.f, ah = ay2 - ay1 + 1.f;
    float cx = ax1 + 0.5f * aw, cy = ay1 + 0.5f * ah;

    float d0 = bbox[(4 * a + 0) * NPOS + p];
    float d1 = bbox[(4 * a + 1) * NPOS + p];
    float d2 = bbox[(4 * a + 2) * NPOS + p];
    float d3 = bbox[(4 * a + 3) * NPOS + p];
    float pcx = d0 * aw + cx, pcy = d1 * ah + cy;
    float pw = expf(d2) * aw, ph = expf(d3) * ah;

    float imh = iminfo[0], imw = iminfo[1], sc = iminfo[2];
    float x1 = fminf(fmaxf(pcx - 0.5f * pw, 0.f), imw - 1.f);
    float y1 = fminf(fmaxf(pcy - 0.5f * ph, 0.f), imh - 1.f);
    float x2 = fminf(fmaxf(pcx + 0.5f * pw, 0.f), imw - 1.f);
    float y2 = fminf(fmaxf(pcy + 0.5f * ph, 0.f), imh - 1.f);
    boxes[idx * 4 + 0] = x1; boxes[idx * 4 + 1] = y1;
    boxes[idx * 4 + 2] = x2; boxes[idx * 4 + 3] = y2;

    float wsz = x2 - x1 + 1.f, hsz = y2 - y1 + 1.f;
    float ms = 16.f * sc;
    float s = (wsz >= ms && hsz >= ms) ? prob : -INFINITY;
    unsigned u = __float_as_uint(s);
    u = (u & 0x80000000u) ? ~u : (u | 0x80000000u);   // monotone flip
    unsigned k32 = ~u;                                 // descending order key
    keys[idx] = ((unsigned long long)k32 << 32) | (unsigned)idx;
}

// ---------------- bitonic sort: global step (j >= 2048) ---------------------
__global__ void bitonic_step(unsigned long long* __restrict__ keys, int j, int k)
{
    int i = blockIdx.x * blockDim.x + threadIdx.x;
    int ixj = i ^ j;
    if (ixj > i && ixj < NSORT) {
        unsigned long long a = keys[i], b = keys[ixj];
        bool up = ((i & k) == 0);
        if ((a > b) == up) { keys[i] = b; keys[ixj] = a; }
    }
}

// ---------------- bitonic sort: LDS-local phases ----------------------------
// mode 0: all phases k=2..2048 (full local sort of each 2048 chunk)
// mode 1: finish phase kbig with j=1024..1 (all pairs block-local)
__global__ __launch_bounds__(1024) void bitonic_local(unsigned long long* __restrict__ keys,
                                                      int mode, int kbig)
{
    __shared__ unsigned long long s[2048];
    const int t = threadIdx.x;
    const int base = blockIdx.x * 2048;
    s[t] = keys[base + t];
    s[t + 1024] = keys[base + t + 1024];
    __syncthreads();
    if (mode == 0) {
        for (int k = 2; k <= 2048; k <<= 1) {
            for (int j = k >> 1; j > 0; j >>= 1) {
                int i = ((t & ~(j - 1)) << 1) | (t & (j - 1));
                int ixj = i + j;
                bool up = (((base + i) & k) == 0);
                unsigned long long a = s[i], b = s[ixj];
                if ((a > b) == up) { s[i] = b; s[ixj] = a; }
                __syncthreads();
            }
        }
    } else {
        for (int j = 1024; j > 0; j >>= 1) {
            int i = ((t & ~(j - 1)) << 1) | (t & (j - 1));
            int ixj = i + j;
            bool up = (((base + i) & kbig) == 0);
            unsigned long long a = s[i], b = s[ixj];
            if ((a > b) == up) { s[i] = b; s[ixj] = a; }
            __syncthreads();
        }
    }
    keys[base + t] = s[t];
    keys[base + t + 1024] = s[t + 1024];
}

// ---------------- gather top-6000 boxes ------------------------------------
__global__ void gather_top(const unsigned long long* __restrict__ keys,
                           const float* __restrict__ boxes, float* __restrict__ tb)
{
    int r = blockIdx.x * blockDim.x + threadIdx.x;
    if (r >= PRE_NMS) return;
    int idx = (int)(keys[r] & 0xffffffffULL);
    ((float4*)tb)[r] = ((const float4*)boxes)[idx];
}

// ---------------- per-row suppression bitmask -------------------------------
__global__ __launch_bounds__(128) void iou_sup(const float* __restrict__ tb,
                                               unsigned long long* __restrict__ sup)
{
    int i = blockIdx.x;
    int wj = threadIdx.x;
    if (wj >= NWORD) return;
    float4 bi = ((const float4*)tb)[i];
    float ai = (bi.z - bi.x + 1.f) * (bi.w - bi.y + 1.f);
    unsigned long long m = 0;
    int jbase = wj * 64;
    for (int b = 0; b < 64; ++b) {
        int j = jbase + b;
        if (j <= i || j >= PRE_NMS) continue;
        float4 bj = ((const float4*)tb)[j];
        float xx1 = fmaxf(bi.x, bj.x), yy1 = fmaxf(bi.y, bj.y);
        float xx2 = fminf(bi.z, bj.z), yy2 = fminf(bi.w, bj.w);
        float iw = fmaxf(xx2 - xx1 + 1.f, 0.f), ih = fmaxf(yy2 - yy1 + 1.f, 0.f);
        float inter = iw * ih;
        float aj = (bj.z - bj.x + 1.f) * (bj.w - bj.y + 1.f);
        float iou = inter / (ai + aj - inter);
        if (iou > 0.7f) m |= (1ULL << b);
    }
    sup[(size_t)i * NWORD + wj] = m;
}

// ---------------- greedy NMS scan: single wave64, register keep-mask --------
// Lane l owns keep-words l and 64+l. sup rows are constant so the row loads
// for i..i+7 are prefetched 8 deep; the serial chain is only shfl+and.
__global__ void nms_wave(const unsigned long long* __restrict__ sup,
                         unsigned long long* __restrict__ keepg)
{
    const int l = threadIdx.x;          // 64 lanes
    const bool hi = (64 + l < NWORD);
    unsigned long long w0 = ~0ULL;
    unsigned long long w1 = hi ? ~0ULL : 0ULL;

    unsigned long long a0, b0, a1, b1, a2, b2, a3, b3, a4, b4, a5, b5, a6, b6, a7, b7;
#define LOADROW(A, B, r) do { \
        A = sup[(size_t)(r) * NWORD + l]; \
        B = hi ? sup[(size_t)(r) * NWORD + 64 + l] : 0ULL; } while (0)
    LOADROW(a0, b0, 0); LOADROW(a1, b1, 1); LOADROW(a2, b2, 2); LOADROW(a3, b3, 3);
    LOADROW(a4, b4, 4); LOADROW(a5, b5, 5); LOADROW(a6, b6, 6); LOADROW(a7, b7, 7);

    for (int g = 0; g < PRE_NMS; g += 8) {
#define STEP(A, B, ii) do { \
        int i = g + (ii); \
        int wi = i >> 6; \
        unsigned long long kw = (wi < 64) ? __shfl(w0, wi) : __shfl(w1, wi - 64); \
        if ((kw >> (i & 63)) & 1ULL) { w0 &= ~(A); w1 &= ~(B); } \
        int nr = i + 8; \
        if (nr < PRE_NMS) LOADROW(A, B, nr); } while (0)
        STEP(a0, b0, 0); STEP(a1, b1, 1); STEP(a2, b2, 2); STEP(a3, b3, 3);
        STEP(a4, b4, 4); STEP(a5, b5, 5); STEP(a6, b6, 6); STEP(a7, b7, 7);
#undef STEP
    }
#undef LOADROW
    if (l == 29) w1 &= (1ULL << 48) - 1ULL;   // word 93: mask bits >= 6000
    keepg[l] = w0;
    if (hi) keepg[64 + l] = w1;
}

// ---------------- select 300 rois (kept first, then unkept, stable) ---------
// rank(kept i)   = #kept before i
// rank(unkept i) = K + #unkept before i     (matches stable argsort of prio)
__global__ __launch_bounds__(128) void select_rois(
    const unsigned long long* __restrict__ keepg,
    const float* __restrict__ tb,
    float* __restrict__ rois, float* __restrict__ out_rois)
{
    __shared__ int wbase[NWORD + 1];
    const int t = threadIdx.x;
    if (t == 0) {
        int s = 0;
        for (int w = 0; w < NWORD; ++w) { wbase[w] = s; s += __popcll(keepg[w]); }
        wbase[NWORD] = s;
    }
    __syncthreads();
    const int K = wbase[NWORD];
    for (int i = t; i < PRE_NMS; i += 128) {
        unsigned long long wd = keepg[i >> 6];
        int bit = i & 63;
        bool kept = (wd >> bit) & 1ULL;
        int before = wbase[i >> 6] + __popcll(wd & ((1ULL << bit) - 1ULL));
        int rank = kept ? before : (K + i - before);
        if (rank < POST_NMS) {
            float4 bx = ((const float4*)tb)[i];
            float* r1 = rois + rank * 5;
            float* r2 = out_rois + rank * 5;
            r1[0] = 0.f; r1[1] = bx.x; r1[2] = bx.y; r1[3] = bx.z; r1[4] = bx.w;
            r2[0] = 0.f; r2[1] = bx.x; r2[2] = bx.y; r2[3] = bx.z; r2[4] = bx.w;
        }
    }
}

// ---------------- ROI max-pool 7x7 ------------------------------------------
__global__ __launch_bounds__(256) void roi_pool(const float* __restrict__ feat,
                                                const float* __restrict__ rois,
                                                float* __restrict__ pooled)
{
    int b = blockIdx.x;
    const float* r = rois + b * 5;
    int x1 = (int)rintf(r[1] * 0.0625f);
    int y1 = (int)rintf(r[2] * 0.0625f);
    int x2 = (int)rintf(r[3] * 0.0625f);
    int y2 = (int)rintf(r[4] * 0.0625f);
    float bh = (float)max(y2 - y1 + 1, 1) / 7.f;
    float bw = (float)max(x2 - x1 + 1, 1) / 7.f;
    for (int o = threadIdx.x; o < 512 * 49; o += 256) {
        int c = o / 49, rem = o - c * 49;
        int ph = rem / 7, pw = rem - ph * 7;
        int hs = min(max((int)floorf(ph * bh) + y1, 0), FH);
        int he = min(max((int)ceilf((ph + 1) * bh) + y1, 0), FH);
        int wst = min(max((int)floorf(pw * bw) + x1, 0), FW);
        int wen = min(max((int)ceilf((pw + 1) * bw) + x1, 0), FW);
        float m = -INFINITY;
        for (int yy = hs; yy < he; ++yy)
            for (int xx = wst; xx < wen; ++xx)
                m = fmaxf(m, feat[c * NPOS + yy * FW + xx]);
        pooled[(size_t)b * 25088 + o] = (he > hs && wen > wst) ? m : 0.f;
    }
}

// ---------------- split-K GEMM: P[s][M,N] = A[M,K_s] * W[N,K_s]^T ------------
// BM=64, BN=256, BK=32, 256 threads, 8x8 thread tile.
// Thread t: rows (t>>5)*8..+8, cols (t&31) + 32*j (j=0..7) -> W reads are
// conflict-free ds_read_b32, A reads broadcast ds_read_b128.
__global__ __launch_bounds__(256) void gemm_splitk(
    const float* __restrict__ A, const float* __restrict__ Wt,
    float* __restrict__ P, int M, int N, int K)
{
    __shared__ float As[32][64];      // [k][m]  8 KB
    __shared__ float Ws[32][256];     // [k][n] 32 KB
    const int t = threadIdx.x;
    const int n0 = blockIdx.x * 256;
    const int m0 = blockIdx.y * 64;
    const int Kc = K / GS;
    const int kbeg = blockIdx.z * Kc;
    const int tn = t & 31, tm = t >> 5;

    float acc[8][8];
#pragma unroll
    for (int i = 0; i < 8; ++i)
#pragma unroll
        for (int j = 0; j < 8; ++j) acc[i][j] = 0.f;

    for (int k0 = kbeg; k0 < kbeg + Kc; k0 += 32) {
        __syncthreads();
        {   // stage W: thread t owns row n0+t, 32 consecutive k
            const float4* wr = (const float4*)(Wt + (size_t)(n0 + t) * K + k0);
#pragma unroll
            for (int q = 0; q < 8; ++q) {
                float4 v = wr[q];
                Ws[4 * q + 0][t] = v.x; Ws[4 * q + 1][t] = v.y;
                Ws[4 * q + 2][t] = v.z; Ws[4 * q + 3][t] = v.w;
            }
        }
#pragma unroll
        for (int u = 0; u < 2; ++u) {   // stage A: 64 rows x 8 float4
            int task = t + u * 256;
            int m = task >> 3, q = task & 7;
            float4 v = make_float4(0.f, 0.f, 0.f, 0.f);
            if (m0 + m < M) v = *(const float4*)(A + (size_t)(m0 + m) * K + k0 + 4 * q);
            As[4 * q + 0][m] = v.x; As[4 * q + 1][m] = v.y;
            As[4 * q + 2][m] = v.z; As[4 * q + 3][m] = v.w;
        }
        __syncthreads();
#pragma unroll 4
        for (int kk = 0; kk < 32; ++kk) {
            float4 av0 = *(const float4*)&As[kk][tm * 8];
            float4 av1 = *(const float4*)&As[kk][tm * 8 + 4];
            float a[8] = {av0.x, av0.y, av0.z, av0.w, av1.x, av1.y, av1.z, av1.w};
            float wv[8];
#pragma unroll
            for (int j = 0; j < 8; ++j) wv[j] = Ws[kk][tn + (j << 5)];
#pragma unroll
            for (int i = 0; i < 8; ++i)
#pragma unroll
                for (int j = 0; j < 8; ++j) acc[i][j] += a[i] * wv[j];
        }
    }

    float* Pp = P + (size_t)blockIdx.z * M * N;
#pragma unroll
    for (int i = 0; i < 8; ++i) {
        int m = m0 + tm * 8 + i;
        if (m < M) {
            float* row = Pp + (size_t)m * N + n0 + tn;
#pragma unroll
            for (int j = 0; j < 8; ++j) row[j << 5] = acc[i][j];
        }
    }
}

// ---------------- split-K reduce + bias + ReLU ------------------------------
__global__ void splitk_reduce(const float* __restrict__ P, const float* __restrict__ bias,
                              float* __restrict__ out, int M, int N, int relu)
{
    int idx = blockIdx.x * 256 + threadIdx.x;
    int total = (M * N) >> 2;
    if (idx >= total) return;
    float4 s = ((const float4*)P)[idx];
#pragma unroll
    for (int g = 1; g < GS; ++g) {
        float4 v = ((const float4*)P)[(size_t)g * total + idx];
        s.x += v.x; s.y += v.y; s.z += v.z; s.w += v.w;
    }
    int n = (idx << 2) % N;
    float4 b = *(const float4*)(bias + n);
    s.x += b.x; s.y += b.y; s.z += b.z; s.w += b.w;
    if (relu) {
        s.x = fmaxf(s.x, 0.f); s.y = fmaxf(s.y, 0.f);
        s.z = fmaxf(s.z, 0.f); s.w = fmaxf(s.w, 0.f);
    }
    ((float4*)out)[idx] = s;
}

// ---------------- small-N FC (cls=21, breg=84) ------------------------------
__global__ void fc_small(const float* __restrict__ A, const float* __restrict__ Wt,
                         const float* __restrict__ bias, float* __restrict__ out,
                         int N, int K)
{
    int m = blockIdx.x, n = threadIdx.x;
    if (n >= N) return;
    const float4* a = (const float4*)(A + (size_t)m * K);
    const float4* w = (const float4*)(Wt + (size_t)n * K);
    float acc = bias[n];
    for (int q = 0; q < K / 4; ++q) {
        float4 av = a[q], wv = w[q];
        acc += av.x * wv.x + av.y * wv.y + av.z * wv.z + av.w * wv.w;
    }
    out[(size_t)m * N + n] = acc;
}

// ---------------- row softmax over 21 classes -------------------------------
__global__ void softmax21(const float* __restrict__ in, float* __restrict__ out)
{
    int r = blockIdx.x * blockDim.x + threadIdx.x;
    if (r >= POST_NMS) return;
    const float* x = in + r * 21;
    float m = x[0];
    for (int j = 1; j < 21; ++j) m = fmaxf(m, x[j]);
    float e[21], s = 0.f;
    for (int j = 0; j < 21; ++j) { e[j] = expf(x[j] - m); s += e[j]; }
    float inv = 1.f / s;
    for (int j = 0; j < 21; ++j) out[r * 21 + j] = e[j] * inv;
}

// ===========================================================================
extern "C" void kernel_launch(void* const* d_in, const int* in_sizes, int n_in,
                              void* d_out, int out_size, void* d_ws, size_t ws_size,
                              hipStream_t stream)
{
    const float* im_data = (const float*)d_in[0];
    const float* im_info = (const float*)d_in[1];
    const float* vw[13]; const float* vb[13];
    for (int i = 0; i < 13; ++i) { vw[i] = (const float*)d_in[2 + 2 * i]; vb[i] = (const float*)d_in[3 + 2 * i]; }
    const float* rpn_w   = (const float*)d_in[28];
    const float* rpn_b   = (const float*)d_in[29];
    const float* score_w = (const float*)d_in[30];
    const float* score_b = (const float*)d_in[31];
    const float* bbox_w  = (const float*)d_in[32];
    const float* bbox_b  = (const float*)d_in[33];
    const float* fc6_w   = (const float*)d_in[34];
    const float* fc6_b   = (const float*)d_in[35];
    const float* fc7_w   = (const float*)d_in[36];
    const float* fc7_b   = (const float*)d_in[37];
    const float* cls_w   = (const float*)d_in[38];
    const float* cls_b   = (const float*)d_in[39];
    const float* breg_w  = (const float*)d_in[40];
    const float* breg_b  = (const float*)d_in[41];

    float* ws = (float*)d_ws;
    // workspace offsets (floats)
    const size_t oA    = 0;                       // 38,400,000 (64*600*1000); reused as split-K partials later
    const size_t oB    = 38400000;                // ping-pong buffer
    const size_t oF    = 76800000;                // feat 512*2294
    const size_t oRPN  = oF    + 1174528;
    const size_t oSC   = oRPN  + 1174528;         // 18*2294
    const size_t oBB   = oSC   + 41292;           // 36*2294
    const size_t oBOX  = oBB   + 82584;           // 20646*4
    const size_t oKEY  = oBOX  + 82584;           // 32768 u64 (as 65536 floats)
    const size_t oTB   = oKEY  + 65536;           // 6000*4
    const size_t oSUP  = oTB   + 24000;           // 6000*94 u64
    const size_t oKEEP = oSUP  + 1128000;         // 94 u64 (padded)
    const size_t oROI  = oKEEP + 256;             // 300*5 (padded)
    const size_t oPOOL = oROI  + 1536;            // 300*25088
    const size_t oH6   = oPOOL + 7526400;         // 300*4096
    const size_t oH7   = oH6   + 1228800;
    const size_t oCLS  = oH7   + 1228800;         // 300*21 (padded)

    float* bufA = ws + oA;
    float* bufB = ws + oB;
    float* feat = ws + oF;
    float* rpn  = ws + oRPN;
    float* scr  = ws + oSC;
    float* bbx  = ws + oBB;
    float* boxes = ws + oBOX;
    unsigned long long* keys = (unsigned long long*)(ws + oKEY);
    float* tb = ws + oTB;
    unsigned long long* sup = (unsigned long long*)(ws + oSUP);
    unsigned long long* keepg = (unsigned long long*)(ws + oKEEP);
    float* rois = ws + oROI;
    float* pooled = ws + oPOOL;
    float* h6 = ws + oH6;
    float* h7 = ws + oH7;
    float* clsb = ws + oCLS;

    float* out = (float*)d_out;          // cls_prob[6300] | bbox_pred[25200] | rois[1500]
    float* out_bbox = out + 6300;
    float* out_rois = out + 31500;

    dim3 cblk(32, 8);
    auto conv = [&](const float* in, const float* w, const float* b, float* o,
                    int C, int H, int W, int K, int relu, int nhwc) {
        dim3 grid((W + 31) / 32, (H + 7) / 8, K / 8);
        conv3x3<<<grid, cblk, 0, stream>>>(in, w, b, o, C, H, W, relu, nhwc);
    };
    auto pool = [&](const float* in, float* o, int C, int H, int W) {
        int total = C * (H / 2) * (W / 2);
        maxpool2<<<(total + 255) / 256, 256, 0, stream>>>(in, o, C, H, W);
    };

    // ---- VGG16 backbone ----
    conv(im_data, vw[0], vb[0], bufA, 3, 600, 1000, 64, 1, 1);
    conv(bufA, vw[1], vb[1], bufB, 64, 600, 1000, 64, 1, 0);
    pool(bufB, bufA, 64, 600, 1000);                       // 300x500
    conv(bufA, vw[2], vb[2], bufB, 64, 300, 500, 128, 1, 0);
    conv(bufB, vw[3], vb[3], bufA, 128, 300, 500, 128, 1, 0);
    pool(bufA, bufB, 128, 300, 500);                       // 150x250
    conv(bufB, vw[4], vb[4], bufA, 128, 150, 250, 256, 1, 0);
    conv(bufA, vw[5], vb[5], bufB, 256, 150, 250, 256, 1, 0);
    conv(bufB, vw[6], vb[6], bufA, 256, 150, 250, 256, 1, 0);
    pool(bufA, bufB, 256, 150, 250);                       // 75x125
    conv(bufB, vw[7], vb[7], bufA, 256, 75, 125, 512, 1, 0);
    conv(bufA, vw[8], vb[8], bufB, 512, 75, 125, 512, 1, 0);
    conv(bufB, vw[9], vb[9], bufA, 512, 75, 125, 512, 1, 0);
    pool(bufA, bufB, 512, 75, 125);                        // 37x62
    conv(bufB, vw[10], vb[10], bufA, 512, FH, FW, 512, 1, 0);
    conv(bufA, vw[11], vb[11], bufB, 512, FH, FW, 512, 1, 0);
    conv(bufB, vw[12], vb[12], feat, 512, FH, FW, 512, 1, 0);

    // ---- RPN ----
    conv(feat, rpn_w, rpn_b, rpn, 512, FH, FW, 512, 1, 0);
    {
        dim3 g((NPOS + 255) / 256, 18);
        conv1x1<<<g, 256, 0, stream>>>(rpn, score_w, score_b, scr, 512, NPOS, 18);
    }
    {
        dim3 g((NPOS + 255) / 256, 36);
        conv1x1<<<g, 256, 0, stream>>>(rpn, bbox_w, bbox_b, bbx, 512, NPOS, 36);
    }

    // ---- proposals ----
    decode_anchors<<<NSORT / 256, 256, 0, stream>>>(scr, bbx, im_info, boxes, keys);
    bitonic_local<<<NSORT / 2048, 1024, 0, stream>>>(keys, 0, 0);       // k=2..2048
    for (int k = 4096; k <= NSORT; k <<= 1) {
        for (int j = k >> 1; j >= 2048; j >>= 1)
            bitonic_step<<<NSORT / 256, 256, 0, stream>>>(keys, j, k);
        bitonic_local<<<NSORT / 2048, 1024, 0, stream>>>(keys, 1, k);   // j=1024..1
    }
    gather_top<<<(PRE_NMS + 255) / 256, 256, 0, stream>>>(keys, boxes, tb);
    iou_sup<<<PRE_NMS, 128, 0, stream>>>(tb, sup);
    nms_wave<<<1, 64, 0, stream>>>(sup, keepg);
    select_rois<<<1, 128, 0, stream>>>(keepg, tb, rois, out_rois);

    // ---- ROI pool + FC head (split-K GEMMs; partials reuse bufA) ----
    roi_pool<<<POST_NMS, 256, 0, stream>>>(feat, rois, pooled);
    {
        float* Pbuf = bufA;                       // GS*300*4096 = 9.83M floats << bufA
        dim3 g6(4096 / 256, (POST_NMS + 63) / 64, GS);
        int rblocks = (POST_NMS * 4096 / 4 + 255) / 256;
        gemm_splitk<<<g6, 256, 0, stream>>>(pooled, fc6_w, Pbuf, POST_NMS, 4096, 25088);
        splitk_reduce<<<rblocks, 256, 0, stream>>>(Pbuf, fc6_b, h6, POST_NMS, 4096, 1);
        gemm_splitk<<<g6, 256, 0, stream>>>(h6, fc7_w, Pbuf, POST_NMS, 4096, 4096);
        splitk_reduce<<<rblocks, 256, 0, stream>>>(Pbuf, fc7_b, h7, POST_NMS, 4096, 1);
    }
    fc_small<<<POST_NMS, 96, 0, stream>>>(h7, cls_w, cls_b, clsb, 21, 4096);
    fc_small<<<POST_NMS, 96, 0, stream>>>(h7, breg_w, breg_b, out_bbox, 84, 4096);
    softmax21<<<(POST_NMS + 255) / 256, 256, 0, stream>>>(clsb, out);
    (void)in_sizes; (void)n_in; (void)out_size; (void)ws_size;
}